// Round 1
// baseline (1066.132 us; speedup 1.0000x reference)
//
#include <hip/hip_runtime.h>
#include <math.h>

#define BATCH 256
#define D 512
#define WPROW ((size_t)(D * D)) // 262144 floats per Wp row

typedef __bf16  bf16x8  __attribute__((ext_vector_type(8)));
typedef float   floatx4 __attribute__((ext_vector_type(4)));

// ---------------- Kernel 1: mapping Linear + L2 normalize ----------------
// grid (256, 2); y==0 -> image path (writes imgT[D][BATCH]), y==1 -> text path
// (writes txtN[BATCH][D]).
__global__ __launch_bounds__(256)
void map_norm_kernel(const float* __restrict__ img_emb,
                     const float* __restrict__ txt_emb,
                     const float* __restrict__ Wi, const float* __restrict__ bi,
                     const float* __restrict__ Wt, const float* __restrict__ bt,
                     float* __restrict__ imgT,
                     float* __restrict__ txtN)
{
    const int b = blockIdx.x;
    const int is_txt = blockIdx.y;
    const int t = threadIdx.x;
    const float* emb = is_txt ? txt_emb : img_emb;
    const float* W   = is_txt ? Wt : Wi;
    const float* bv  = is_txt ? bt : bi;

    __shared__ float row[D];
    row[t]       = emb[(size_t)b * D + t];
    row[t + 256] = emb[(size_t)b * D + t + 256];
    __syncthreads();

    const int k0 = t, k1 = t + 256;
    float acc0 = bv[k0], acc1 = bv[k1];
    const float4* w0 = (const float4*)(W + (size_t)k0 * D);
    const float4* w1 = (const float4*)(W + (size_t)k1 * D);
    const float4* r4 = (const float4*)row;
#pragma unroll 8
    for (int p = 0; p < D / 4; ++p) {
        float4 rv = r4[p];
        float4 a  = w0[p];
        float4 c  = w1[p];
        acc0 += a.x * rv.x + a.y * rv.y + a.z * rv.z + a.w * rv.w;
        acc1 += c.x * rv.x + c.y * rv.y + c.z * rv.z + c.w * rv.w;
    }

    float ss = acc0 * acc0 + acc1 * acc1;
#pragma unroll
    for (int o = 32; o > 0; o >>= 1) ss += __shfl_down(ss, o);
    __shared__ float red[4];
    if ((t & 63) == 0) red[t >> 6] = ss;
    __syncthreads();
    float total = red[0] + red[1] + red[2] + red[3];
    float inv = 1.0f / fmaxf(sqrtf(total), 1e-12f);
    float v0 = acc0 * inv, v1 = acc1 * inv;

    if (is_txt) {
        txtN[(size_t)b * D + k0] = v0;
        txtN[(size_t)b * D + k1] = v1;
    } else {
        imgT[(size_t)k0 * BATCH + b] = v0;
        imgT[(size_t)k1 * BATCH + b] = v1;
    }
}

// ---------------- Kernel 2: streaming bilinear GEMM ----------------
// C[b,k] = sum_c P[b,c] * Wp[k,c],  P[b, i*512+j] = img[b,i]*txt[b,j].
// Mtile=256 (full batch, Wp read exactly once), Ntile=64, split-K=64.
// 512 WGs x 256 threads. A-frags built in registers from txt (fp32, reused
// across 8 i-blocks) scaled by img scalar; B-frags loaded fp32x8 from global
// and converted to bf16; no LDS, no barriers. Split-K reduced via atomicAdd.
__global__ __launch_bounds__(256, 2)
void bilinear_kernel(const float* __restrict__ txtN,  // [BATCH][D]
                     const float* __restrict__ imgT,  // [D][BATCH]
                     const float* __restrict__ Wp,    // [D][D*D]
                     float* __restrict__ feats)       // [BATCH][D], pre-zeroed
{
    const int wg   = blockIdx.x;
    const int nt   = wg & 7;    // N-tile: output cols [nt*64, +64)
    const int ks   = wg >> 3;   // K-split: i in [ks*8, ks*8+8)
    const int lane = threadIdx.x & 63;
    const int wave = threadIdx.x >> 6;
    const int lane15 = lane & 15;
    const int quad   = lane >> 4;

    const int brow0 = wave * 64 + lane15;  // + m*16 -> A row (batch b)
    const int n0    = nt * 64 + lane15;    // + n*16 -> B row (output k)
    const int i0    = ks * 8;

    floatx4 zero4 = {0.f, 0.f, 0.f, 0.f};
    floatx4 acc[4][4];
#pragma unroll
    for (int m = 0; m < 4; ++m)
#pragma unroll
        for (int n = 0; n < 4; ++n) acc[m][n] = zero4;

    // img scalars for all (m, ii) — reused across every jstep
    float img_s[4][8];
#pragma unroll
    for (int ii = 0; ii < 8; ++ii)
#pragma unroll
        for (int m = 0; m < 4; ++m)
            img_s[m][ii] = imgT[(size_t)(i0 + ii) * BATCH + brow0 + m * 16];

    // Wp row bases for this lane's 4 N-subtiles (offset to i-block start)
    const float* wpr[4];
#pragma unroll
    for (int n = 0; n < 4; ++n)
        wpr[n] = Wp + (size_t)(n0 + n * 16) * WPROW + (size_t)i0 * D;

    for (int jstep = 0; jstep < 16; ++jstep) {
        const int j0 = jstep * 32 + quad * 8;  // this lane's 8 j's (K-dim)

        // txt fragments (fp32), reused for all 8 i-blocks
        float4 tf[4][2];
#pragma unroll
        for (int m = 0; m < 4; ++m) {
            const float4* p =
                (const float4*)(txtN + (size_t)(brow0 + m * 16) * D + j0);
            tf[m][0] = p[0];
            tf[m][1] = p[1];
        }

#pragma unroll
        for (int ii = 0; ii < 8; ++ii) {
            // B fragments: Wp[n-row][i*512 + j0 .. +7] fp32 -> bf16
            bf16x8 bfr[4];
#pragma unroll
            for (int n = 0; n < 4; ++n) {
                const float4* p = (const float4*)(wpr[n] + (size_t)ii * D + j0);
                float4 x = p[0];
                float4 y = p[1];
                bf16x8 v;
                v[0] = (__bf16)x.x; v[1] = (__bf16)x.y;
                v[2] = (__bf16)x.z; v[3] = (__bf16)x.w;
                v[4] = (__bf16)y.x; v[5] = (__bf16)y.y;
                v[6] = (__bf16)y.z; v[7] = (__bf16)y.w;
                bfr[n] = v;
            }
#pragma unroll
            for (int m = 0; m < 4; ++m) {
                const float s = img_s[m][ii];
                bf16x8 a;
                a[0] = (__bf16)(s * tf[m][0].x);
                a[1] = (__bf16)(s * tf[m][0].y);
                a[2] = (__bf16)(s * tf[m][0].z);
                a[3] = (__bf16)(s * tf[m][0].w);
                a[4] = (__bf16)(s * tf[m][1].x);
                a[5] = (__bf16)(s * tf[m][1].y);
                a[6] = (__bf16)(s * tf[m][1].z);
                a[7] = (__bf16)(s * tf[m][1].w);
#pragma unroll
                for (int n = 0; n < 4; ++n)
                    acc[m][n] = __builtin_amdgcn_mfma_f32_16x16x32_bf16(
                        a, bfr[n], acc[m][n], 0, 0, 0);
            }
        }
    }

    // Split-K reduction. C/D layout: col = lane&15, row = quad*4 + reg.
#pragma unroll
    for (int m = 0; m < 4; ++m)
#pragma unroll
        for (int n = 0; n < 4; ++n)
#pragma unroll
            for (int r = 0; r < 4; ++r) {
                int brow = wave * 64 + m * 16 + quad * 4 + r;
                int kcol = n0 + n * 16;
                atomicAdd(&feats[(size_t)brow * D + kcol], acc[m][n][r]);
            }
}

// ---------------- Kernel 3: bias + ReLU + classifier + sigmoid ----------------
__global__ __launch_bounds__(256)
void epilogue_kernel(const float* __restrict__ feats,
                     const float* __restrict__ bp,
                     const float* __restrict__ Wc,
                     const float* __restrict__ bc,
                     float* __restrict__ out)
{
    const int b = blockIdx.x;
    const int t = threadIdx.x;
    float v0 = fmaxf(feats[(size_t)b * D + t] + bp[t], 0.f) * Wc[t];
    float v1 = fmaxf(feats[(size_t)b * D + t + 256] + bp[t + 256], 0.f) * Wc[t + 256];
    float s = v0 + v1;
#pragma unroll
    for (int o = 32; o > 0; o >>= 1) s += __shfl_down(s, o);
    __shared__ float red[4];
    if ((t & 63) == 0) red[t >> 6] = s;
    __syncthreads();
    if (t == 0) {
        float tot = red[0] + red[1] + red[2] + red[3] + bc[0];
        out[b] = 1.0f / (1.0f + expf(-tot));
    }
}

extern "C" void kernel_launch(void* const* d_in, const int* in_sizes, int n_in,
                              void* d_out, int out_size, void* d_ws, size_t ws_size,
                              hipStream_t stream) {
    const float* image_embeds = (const float*)d_in[0];
    const float* text_embeds  = (const float*)d_in[1];
    const float* Wi = (const float*)d_in[2];
    const float* bi = (const float*)d_in[3];
    const float* Wt = (const float*)d_in[4];
    const float* bt = (const float*)d_in[5];
    const float* Wp = (const float*)d_in[6];
    const float* bp = (const float*)d_in[7];
    const float* Wc = (const float*)d_in[8];
    const float* bc = (const float*)d_in[9];
    float* out = (float*)d_out;

    float* txtN  = (float*)d_ws;            // 256*512 f32
    float* imgT  = txtN + BATCH * D;        // 512*256 f32
    float* feats = imgT + D * BATCH;        // 256*512 f32

    hipMemsetAsync(feats, 0, (size_t)BATCH * D * sizeof(float), stream);
    map_norm_kernel<<<dim3(BATCH, 2), 256, 0, stream>>>(
        image_embeds, text_embeds, Wi, bi, Wt, bt, imgT, txtN);
    bilinear_kernel<<<dim3(512), 256, 0, stream>>>(txtN, imgT, Wp, feats);
    epilogue_kernel<<<dim3(BATCH), 256, 0, stream>>>(feats, bp, Wc, bc, out);
}

// Round 2
// 936.245 us; speedup vs baseline: 1.1387x; 1.1387x over previous
//
#include <hip/hip_runtime.h>
#include <math.h>

#define BATCH 256
#define D 512
#define WPROW ((size_t)(D * D)) // 262144 floats per Wp row
#define BK 128                  // fp32 per row per K-chunk (512 B)
#define NTILE 64
#define NCHUNK 32               // per-WG K range = 32*128 = 4096

typedef __bf16  bf16x8  __attribute__((ext_vector_type(8)));
typedef float   floatx4 __attribute__((ext_vector_type(4)));

// ---------------- Kernel 1: mapping Linear + L2 normalize ----------------
__global__ __launch_bounds__(256)
void map_norm_kernel(const float* __restrict__ img_emb,
                     const float* __restrict__ txt_emb,
                     const float* __restrict__ Wi, const float* __restrict__ bi,
                     const float* __restrict__ Wt, const float* __restrict__ bt,
                     float* __restrict__ imgT,
                     float* __restrict__ txtN)
{
    const int b = blockIdx.x;
    const int is_txt = blockIdx.y;
    const int t = threadIdx.x;
    const float* emb = is_txt ? txt_emb : img_emb;
    const float* W   = is_txt ? Wt : Wi;
    const float* bv  = is_txt ? bt : bi;

    __shared__ float row[D];
    row[t]       = emb[(size_t)b * D + t];
    row[t + 256] = emb[(size_t)b * D + t + 256];
    __syncthreads();

    const int k0 = t, k1 = t + 256;
    float acc0 = bv[k0], acc1 = bv[k1];
    const float4* w0 = (const float4*)(W + (size_t)k0 * D);
    const float4* w1 = (const float4*)(W + (size_t)k1 * D);
    const float4* r4 = (const float4*)row;
#pragma unroll 8
    for (int p = 0; p < D / 4; ++p) {
        float4 rv = r4[p];
        float4 a  = w0[p];
        float4 c  = w1[p];
        acc0 += a.x * rv.x + a.y * rv.y + a.z * rv.z + a.w * rv.w;
        acc1 += c.x * rv.x + c.y * rv.y + c.z * rv.z + c.w * rv.w;
    }

    float ss = acc0 * acc0 + acc1 * acc1;
#pragma unroll
    for (int o = 32; o > 0; o >>= 1) ss += __shfl_down(ss, o);
    __shared__ float red[4];
    if ((t & 63) == 0) red[t >> 6] = ss;
    __syncthreads();
    float total = red[0] + red[1] + red[2] + red[3];
    float inv = 1.0f / fmaxf(sqrtf(total), 1e-12f);
    float v0 = acc0 * inv, v1 = acc1 * inv;

    if (is_txt) {
        txtN[(size_t)b * D + k0] = v0;
        txtN[(size_t)b * D + k1] = v1;
    } else {
        imgT[(size_t)k0 * BATCH + b] = v0;
        imgT[(size_t)k1 * BATCH + b] = v1;
    }
}

// ---------------- Kernel 2: streaming bilinear GEMM w/ async LDS DMA ------
// C[b,k] = sum_c P[b,c]*Wp[k,c], P[b,i*512+j] = img[b,i]*txt[b,j].
// 512 WGs (2/CU): nt = wg&7 picks 64 Wp rows, ks = wg>>3 picks 4096 K-cols.
// Wp staged fp32 into double-buffered LDS via global_load_lds (16B/lane,
// 512B-contiguous per row). 16B blocks XOR-swizzled by (row&7) on the FETCH
// side so LDS frag reads spread across all 8 bank groups (2-way = free).
__global__ __launch_bounds__(256, 2)
void bilinear_kernel(const float* __restrict__ txtN,  // [BATCH][D]
                     const float* __restrict__ imgT,  // [D][BATCH]
                     const float* __restrict__ Wp,    // [D][D*D]
                     float* __restrict__ feats)       // [BATCH][D], pre-zeroed
{
    __shared__ float lds[2][NTILE * BK];   // 2 x 32 KB

    const int wg   = blockIdx.x;
    const int nt   = wg & 7;
    const int ks   = wg >> 3;
    const int tid  = threadIdx.x;
    const int lane = tid & 63;
    const int wave = tid >> 6;
    const int lane15 = lane & 15;
    const int quad   = lane >> 4;

    const int    n0     = nt * NTILE;
    const size_t kbase0 = (size_t)ks * (NCHUNK * BK);
    const int    i0     = ks * 8;          // 4096 k = 8 i-values
    const int    brow0  = wave * 64 + lane15;

    // DMA lane mapping: instr k covers rows 2k,2k+1 of the tile.
    const int dma_rowoff = lane >> 5;   // 0/1
    const int dma_bslot  = lane & 31;   // 16B block slot within 512B row seg

    floatx4 acc[4][4];
#pragma unroll
    for (int m = 0; m < 4; ++m)
#pragma unroll
        for (int n = 0; n < 4; ++n) acc[m][n] = (floatx4){0.f, 0.f, 0.f, 0.f};

    auto stage = [&](int cidx, int bufsel) {
        const size_t kb = kbase0 + (size_t)cidx * BK;
#pragma unroll
        for (int u = 0; u < 8; ++u) {
            const int k   = wave * 8 + u;
            const int row = 2 * k + dma_rowoff;
            const int bg  = dma_bslot ^ (row & 7);      // fetch-side swizzle
            const float* gp = Wp + (size_t)(n0 + row) * WPROW + kb + (size_t)bg * 4;
            float* lp = &lds[bufsel][k * 256];          // 1KB per instr
            __builtin_amdgcn_global_load_lds(
                (__attribute__((address_space(1))) void*)(uintptr_t)gp,
                (__attribute__((address_space(3))) void*)(uintptr_t)lp,
                16, 0, 0);
        }
    };

    stage(0, 0);
    __syncthreads();

    for (int c = 0; c < NCHUNK; ++c) {
        if (c + 1 < NCHUNK) stage(c + 1, (c + 1) & 1);

        const float* buf = lds[c & 1];
        const int i  = i0 + (c >> 2);
        const int jb = (c & 3) * BK;

        float simg[4];
#pragma unroll
        for (int m = 0; m < 4; ++m)
            simg[m] = imgT[(size_t)i * BATCH + brow0 + m * 16];

#pragma unroll
        for (int t = 0; t < 4; ++t) {
            const int j0 = jb + t * 32 + quad * 8;

            float4 ta[4], tb[4];
#pragma unroll
            for (int m = 0; m < 4; ++m) {
                const float4* p =
                    (const float4*)(txtN + (size_t)(brow0 + m * 16) * D + j0);
                ta[m] = p[0];
                tb[m] = p[1];
            }

            bf16x8 bfr[4];
#pragma unroll
            for (int n = 0; n < 4; ++n) {
                const int r  = n * 16 + lane15;
                const int bc = t * 8 + quad * 2;
                const int sw = r & 7;
                const float4 x = *(const float4*)(buf + r * BK + ((bc    ) ^ sw) * 4);
                const float4 y = *(const float4*)(buf + r * BK + ((bc + 1) ^ sw) * 4);
                bf16x8 v;
                v[0] = (__bf16)x.x; v[1] = (__bf16)x.y;
                v[2] = (__bf16)x.z; v[3] = (__bf16)x.w;
                v[4] = (__bf16)y.x; v[5] = (__bf16)y.y;
                v[6] = (__bf16)y.z; v[7] = (__bf16)y.w;
                bfr[n] = v;
            }

#pragma unroll
            for (int m = 0; m < 4; ++m) {
                const float s = simg[m];
                bf16x8 a;
                a[0] = (__bf16)(s * ta[m].x);
                a[1] = (__bf16)(s * ta[m].y);
                a[2] = (__bf16)(s * ta[m].z);
                a[3] = (__bf16)(s * ta[m].w);
                a[4] = (__bf16)(s * tb[m].x);
                a[5] = (__bf16)(s * tb[m].y);
                a[6] = (__bf16)(s * tb[m].z);
                a[7] = (__bf16)(s * tb[m].w);
#pragma unroll
                for (int n = 0; n < 4; ++n)
                    acc[m][n] = __builtin_amdgcn_mfma_f32_16x16x32_bf16(
                        a, bfr[n], acc[m][n], 0, 0, 0);
            }
        }
        __syncthreads();
    }

    // Split-K reduction. C/D layout: col = lane&15, row = quad*4 + reg.
#pragma unroll
    for (int m = 0; m < 4; ++m)
#pragma unroll
        for (int n = 0; n < 4; ++n)
#pragma unroll
            for (int r = 0; r < 4; ++r) {
                int brow = wave * 64 + m * 16 + quad * 4 + r;
                int kcol = n0 + n * 16 + lane15;
                atomicAdd(&feats[(size_t)brow * D + kcol], acc[m][n][r]);
            }
}

// ---------------- Kernel 3: bias + ReLU + classifier + sigmoid ------------
__global__ __launch_bounds__(256)
void epilogue_kernel(const float* __restrict__ feats,
                     const float* __restrict__ bp,
                     const float* __restrict__ Wc,
                     const float* __restrict__ bc,
                     float* __restrict__ out)
{
    const int b = blockIdx.x;
    const int t = threadIdx.x;
    float v0 = fmaxf(feats[(size_t)b * D + t] + bp[t], 0.f) * Wc[t];
    float v1 = fmaxf(feats[(size_t)b * D + t + 256] + bp[t + 256], 0.f) * Wc[t + 256];
    float s = v0 + v1;
#pragma unroll
    for (int o = 32; o > 0; o >>= 1) s += __shfl_down(s, o);
    __shared__ float red[4];
    if ((t & 63) == 0) red[t >> 6] = s;
    __syncthreads();
    if (t == 0) {
        float tot = red[0] + red[1] + red[2] + red[3] + bc[0];
        out[b] = 1.0f / (1.0f + expf(-tot));
    }
}

extern "C" void kernel_launch(void* const* d_in, const int* in_sizes, int n_in,
                              void* d_out, int out_size, void* d_ws, size_t ws_size,
                              hipStream_t stream) {
    const float* image_embeds = (const float*)d_in[0];
    const float* text_embeds  = (const float*)d_in[1];
    const float* Wi = (const float*)d_in[2];
    const float* bi = (const float*)d_in[3];
    const float* Wt = (const float*)d_in[4];
    const float* bt = (const float*)d_in[5];
    const float* Wp = (const float*)d_in[6];
    const float* bp = (const float*)d_in[7];
    const float* Wc = (const float*)d_in[8];
    const float* bc = (const float*)d_in[9];
    float* out = (float*)d_out;

    float* txtN  = (float*)d_ws;            // 256*512 f32
    float* imgT  = txtN + BATCH * D;        // 512*256 f32
    float* feats = imgT + D * BATCH;        // 256*512 f32

    hipMemsetAsync(feats, 0, (size_t)BATCH * D * sizeof(float), stream);
    map_norm_kernel<<<dim3(BATCH, 2), 256, 0, stream>>>(
        image_embeds, text_embeds, Wi, bi, Wt, bt, imgT, txtN);
    bilinear_kernel<<<dim3(512), 256, 0, stream>>>(txtN, imgT, Wp, feats);
    epilogue_kernel<<<dim3(BATCH), 256, 0, stream>>>(feats, bp, Wc, bc, out);
}